// Round 1
// 1528.801 us; speedup vs baseline: 1.2857x; 1.2857x over previous
//
#include <hip/hip_runtime.h>
#include <cstdint>
#include <cstddef>

#define D_MODEL 2048
#define NUM_CLASSES 50257
#define N_PAD 50304          // 393*128
#define N_BASIS 8
#define RANK 4
#define HIDDEN 128
#define B_ROWS 2048
#define KE 2080              // D_MODEL + N_BASIS*RANK
#define NTILES 6288          // (B_ROWS/128)*(N_PAD/128) = 16*393
#define LN_EPS 1e-5f

typedef short short8 __attribute__((ext_vector_type(8)));
typedef float f32x4 __attribute__((ext_vector_type(4)));

__device__ __forceinline__ uint16_t f2bf(float f) {
    union { float f; uint32_t u; } c; c.f = f;
    uint32_t r = c.u + 0x7FFFu + ((c.u >> 16) & 1u);   // round-to-nearest-even
    return (uint16_t)(r >> 16);
}

__device__ __forceinline__ short8 pack8(float4 a, float4 b) {
    union { short8 v; uint16_t u[8]; } p;
    p.u[0] = f2bf(a.x); p.u[1] = f2bf(a.y); p.u[2] = f2bf(a.z); p.u[3] = f2bf(a.w);
    p.u[4] = f2bf(b.x); p.u[5] = f2bf(b.y); p.u[6] = f2bf(b.z); p.u[7] = f2bf(b.w);
    return p.v;
}

__device__ __forceinline__ short8 zero8() {
    union { short8 s; uint16_t u[8]; } z;
    #pragma unroll
    for (int i = 0; i < 8; i++) z.u[i] = 0;
    return z.s;
}

__device__ __forceinline__ void async16(const void* g, void* l) {
    __builtin_amdgcn_global_load_lds(
        (const __attribute__((address_space(1))) unsigned int*)g,
        (__attribute__((address_space(3))) unsigned int*)l, 16, 0, 0);
}

// ---- x (fp32, 2048x2048) -> Aext bf16 cols [0,2048), ld=KE ----
__global__ void k_cvt_x(const float* __restrict__ x, uint16_t* __restrict__ Aext) {
    int chunk = blockIdx.x * 256 + threadIdx.x;     // 2048*256 chunks of 8
    int b = chunk >> 8, c8 = (chunk & 255) * 8;
    const float4* src = (const float4*)(x + (size_t)b * D_MODEL + c8);
    float4 f0 = src[0], f1 = src[1];
    *(short8*)(Aext + (size_t)b * KE + c8) = pack8(f0, f1);
}

// ---- generic fp32 transpose: src[R][C] -> dst[C][R], write-coalesced ----
__global__ void k_transpose(const float* __restrict__ src, float* __restrict__ dst,
                            int R, int C) {
    int i = blockIdx.x * 256 + threadIdx.x;
    if (i >= R * C) return;
    int c = i / R, r = i - c * R;
    dst[i] = src[(size_t)r * C + c];
}

// ---- base_w + basis_B -> Bext bf16 (full path): cols [0,2048) from base_w,
//      cols [2048,2080) = basis_B[nb,row,r] at col 2048+nb*4+r; pad rows zeroed ----
__global__ void k_cvt_bw(const float* __restrict__ bw, const float* __restrict__ bB,
                         uint16_t* __restrict__ Bext) {
    int row = blockIdx.x;                 // 0..N_PAD-1
    int c8 = threadIdx.x * 8;             // 256 threads cover 2048 cols
    short8 v;
    if (row < NUM_CLASSES) {
        const float4* src = (const float4*)(bw + (size_t)row * D_MODEL + c8);
        v = pack8(src[0], src[1]);
    } else v = zero8();
    *(short8*)(Bext + (size_t)row * KE + c8) = v;
    if (threadIdx.x < 4) {                // extension chunk t covers nb = 2t, 2t+1
        int t = threadIdx.x;
        short8 e;
        if (row < NUM_CLASSES) {
            float4 v0 = *(const float4*)(bB + ((size_t)(2 * t)     * NUM_CLASSES + row) * RANK);
            float4 v1 = *(const float4*)(bB + ((size_t)(2 * t + 1) * NUM_CLASSES + row) * RANK);
            e = pack8(v0, v1);
        } else e = zero8();
        *(short8*)(Bext + (size_t)row * KE + D_MODEL + t * 8) = e;
    }
}

// ---- fallback: basis_B -> Bbt[row][32] bf16 ----
__global__ void k_cvt_bbt(const float* __restrict__ bB, uint16_t* __restrict__ dst,
                          int ld, int coloff) {
    int row = blockIdx.x * 256 + threadIdx.x;
    if (row >= N_PAD) return;
    union { short8 v[4]; uint16_t u[32]; } p;
    if (row < NUM_CLASSES) {
        #pragma unroll
        for (int nb = 0; nb < N_BASIS; nb++) {
            float4 v = *(const float4*)(bB + ((size_t)nb * NUM_CLASSES + row) * RANK);
            p.u[nb*4+0] = f2bf(v.x); p.u[nb*4+1] = f2bf(v.y);
            p.u[nb*4+2] = f2bf(v.z); p.u[nb*4+3] = f2bf(v.w);
        }
    } else {
        #pragma unroll
        for (int i = 0; i < 32; i++) p.u[i] = 0;
    }
    uint16_t* d = dst + (size_t)row * ld + coloff;
    #pragma unroll
    for (int i = 0; i < 4; i++) *(short8*)(d + i * 8) = p.v[i];
}

// ---- context MLP: linear -> LN -> exact GELU -> linear -> coeffs (2048x8 fp32)
//      ctx_wT is [D_MODEL][HIDDEN] so lane-j reads are coalesced ----
__global__ void k_ctx(const float* __restrict__ context, const float* __restrict__ ctx_wT,
                      const float* __restrict__ ctx_b, const float* __restrict__ ln_g,
                      const float* __restrict__ ln_b, const float* __restrict__ coeff_w,
                      const float* __restrict__ coeff_b, float* __restrict__ coeffs) {
    __shared__ float sctx[D_MODEL];
    __shared__ float s1[HIDDEN], s2[HIDDEN], sh[HIDDEN];
    int tid = threadIdx.x, b = blockIdx.x;
    const float4* csrc = (const float4*)(context + (size_t)b * D_MODEL);
    for (int i = tid; i < D_MODEL / 4; i += HIDDEN) ((float4*)sctx)[i] = csrc[i];
    __syncthreads();
    float a0 = 0.f, a1 = 0.f, a2 = 0.f, a3 = 0.f;
    #pragma unroll 4
    for (int k = 0; k < D_MODEL; k += 4) {
        a0 += ctx_wT[(size_t)(k + 0) * HIDDEN + tid] * sctx[k + 0];
        a1 += ctx_wT[(size_t)(k + 1) * HIDDEN + tid] * sctx[k + 1];
        a2 += ctx_wT[(size_t)(k + 2) * HIDDEN + tid] * sctx[k + 2];
        a3 += ctx_wT[(size_t)(k + 3) * HIDDEN + tid] * sctx[k + 3];
    }
    float h0 = (a0 + a1) + (a2 + a3) + ctx_b[tid];
    s1[tid] = h0; s2[tid] = h0 * h0;
    __syncthreads();
    for (int off = HIDDEN / 2; off > 0; off >>= 1) {
        if (tid < off) { s1[tid] += s1[tid + off]; s2[tid] += s2[tid + off]; }
        __syncthreads();
    }
    float mu  = s1[0] * (1.f / HIDDEN);
    float var = s2[0] * (1.f / HIDDEN) - mu * mu;
    float hn = (h0 - mu) * rsqrtf(var + LN_EPS) * ln_g[tid] + ln_b[tid];
    float h = 0.5f * hn * (1.f + erff(hn * 0.70710678118654752f));
    sh[tid] = h;
    __syncthreads();
    if (tid < N_BASIS) {
        const float* cw = coeff_w + tid * HIDDEN;
        float a = 0.f;
        #pragma unroll 4
        for (int k = 0; k < HIDDEN; k++) a += cw[k] * sh[k];
        coeffs[b * N_BASIS + tid] = a + coeff_b[tid];
    }
}

// ---- t = x @ basis_A^T ; z_r = sum_nb coeffs*t ; u = coeffs (x) z -> Aext cols [2048,2080)
//      basis_AT is [D_MODEL][32] so lane-j reads are coalesced ----
__global__ void k_zu(const float* __restrict__ x, const float* __restrict__ basis_AT,
                     const float* __restrict__ coeffs, uint16_t* __restrict__ Aext) {
    __shared__ float sx[D_MODEL];
    __shared__ float part[128];
    __shared__ float st[32];
    __shared__ float sz[RANK];
    int tid = threadIdx.x, b = blockIdx.x;
    const float4* xs = (const float4*)(x + (size_t)b * D_MODEL);
    for (int i = tid; i < D_MODEL / 4; i += 128) ((float4*)sx)[i] = xs[i];
    __syncthreads();
    int j = tid & 31, s = tid >> 5;       // 32 outputs x 4 K-slices
    int k0 = s * (D_MODEL / 4);
    float a0 = 0.f, a1 = 0.f, a2 = 0.f, a3 = 0.f;
    #pragma unroll 4
    for (int k = 0; k < D_MODEL / 4; k += 4) {
        a0 += basis_AT[(size_t)(k0 + k + 0) * 32 + j] * sx[k0 + k + 0];
        a1 += basis_AT[(size_t)(k0 + k + 1) * 32 + j] * sx[k0 + k + 1];
        a2 += basis_AT[(size_t)(k0 + k + 2) * 32 + j] * sx[k0 + k + 2];
        a3 += basis_AT[(size_t)(k0 + k + 3) * 32 + j] * sx[k0 + k + 3];
    }
    part[tid] = (a0 + a1) + (a2 + a3);
    __syncthreads();
    if (tid < 32) st[tid] = part[tid] + part[tid + 32] + part[tid + 64] + part[tid + 96];
    __syncthreads();
    if (tid < RANK) {
        float z = 0.f;
        #pragma unroll
        for (int nb = 0; nb < N_BASIS; nb++) z += coeffs[b * N_BASIS + nb] * st[nb * RANK + tid];
        sz[tid] = z;
    }
    __syncthreads();
    if (tid < 32) {
        int nb = tid >> 2, r = tid & 3;
        float u = coeffs[b * N_BASIS + nb] * sz[r];
        Aext[(size_t)b * KE + D_MODEL + tid] = f2bf(u);
    }
}

// ---- main GEMM: C[m,n] = sum_k Aext[m,k]*B[n,k] + base_b[n]
//      128x128 tile, BK=32, double-buffered LDS (prefetch next K-step during MFMA),
//      one barrier per K-step, XCD-aware 1D block swizzle (bn-groups stay on one XCD) ----
template<bool FULLB>
__global__ __launch_bounds__(256) void k_gemm(
        const uint16_t* __restrict__ Aext,   // B_ROWS x KE bf16
        const uint16_t* __restrict__ Bbuf,   // FULLB: N_PAD x KE ; else Bbt N_PAD x 32
        const float* __restrict__ bw,        // fp32 base_w (fallback staging)
        const float* __restrict__ base_b,
        float* __restrict__ out) {
    __shared__ uint16_t sA[2][128 * 32];
    __shared__ uint16_t sB[2][128 * 32];
    const int tid = threadIdx.x;
    const int lane = tid & 63, w = tid >> 6;
    // XCD swizzle: 6288 = 8 * 786 exactly (bijective). Blocks on one XCD get a
    // contiguous tile range; tile = bn*16+bm (bm fastest) so each bn-group's 16
    // blocks land on the same XCD -> B-panel L2-resident.
    const int l = blockIdx.x;
    const int tile = (l & 7) * (NTILES / 8) + (l >> 3);
    const int bm = tile & 15, bn = tile >> 4;
    const int wm = (w >> 1) * 64, wn = (w & 1) * 64;
    const int sr = tid >> 2, sc = (tid & 3) * 8;   // staging: rows sr & sr+64, col chunk sc
    f32x4 acc[4][4] = {};

    const uint16_t* gA = Aext + (size_t)(bm * 128 + sr) * KE + sc;

    auto stageA = [&](int kk, int sel) {
        async16(gA + kk, &sA[sel][w * 512]);
        async16(gA + (size_t)64 * KE + kk, &sA[sel][2048 + w * 512]);
    };
    auto stageBfull = [&](int kk, int sel) {
        const uint16_t* gB = Bbuf + (size_t)(bn * 128 + sr) * KE + sc + kk;
        async16(gB, &sB[sel][w * 512]);
        async16(gB + (size_t)64 * KE, &sB[sel][2048 + w * 512]);
    };
    auto stageBfb = [&](int kk, int sel) {
        if (kk < D_MODEL) {
            #pragma unroll
            for (int it = 0; it < 2; it++) {
                int rr = it * 64 + sr;
                int gr = bn * 128 + rr;
                short8 v;
                if (gr < NUM_CLASSES) {
                    const float4* src = (const float4*)(bw + (size_t)gr * D_MODEL + kk + sc);
                    v = pack8(src[0], src[1]);
                } else v = zero8();
                *(short8*)(&sB[sel][rr * 32 + sc]) = v;
            }
        } else {
            #pragma unroll
            for (int it = 0; it < 2; it++) {
                int rr = it * 64 + sr;
                async16(Bbuf + (size_t)(bn * 128 + rr) * 32 + (kk - D_MODEL) + sc,
                        &sB[sel][it * 2048 + w * 512]);
            }
        }
    };

    // prologue: stage K-step 0 into buffer 0
    stageA(0, 0);
    if constexpr (FULLB) stageBfull(0, 0); else stageBfb(0, 0);
    __syncthreads();                       // vmcnt(0)+lgkmcnt(0) drain + barrier

    int cur = 0;
    for (int kk = 0; kk < KE; kk += 32) {
        int nxt = cur ^ 1;
        if (kk + 32 < KE) {                // issue next tile's loads BEFORE compute
            stageA(kk + 32, nxt);
            if constexpr (FULLB) stageBfull(kk + 32, nxt); else stageBfb(kk + 32, nxt);
        }
        const uint16_t* pA = sA[cur] + (lane >> 4) * 8;
        const uint16_t* pB = sB[cur] + (lane >> 4) * 8;
        short8 af[4], bfv[4];
        #pragma unroll
        for (int i = 0; i < 4; i++)
            af[i] = *(const short8*)(pA + (wm + i * 16 + (lane & 15)) * 32);
        #pragma unroll
        for (int j = 0; j < 4; j++)
            bfv[j] = *(const short8*)(pB + (wn + j * 16 + (lane & 15)) * 32);
        #pragma unroll
        for (int i = 0; i < 4; i++)
            #pragma unroll
            for (int j = 0; j < 4; j++)
                acc[i][j] = __builtin_amdgcn_mfma_f32_16x16x32_bf16(af[i], bfv[j], acc[i][j], 0, 0, 0);
        __syncthreads();                   // drains next-tile vmcnt + everyone's ds_reads
        cur = nxt;
    }

    const int rb = bm * 128 + wm + ((lane >> 4) << 2);
    const int cb = bn * 128 + wn + (lane & 15);
    #pragma unroll
    for (int j = 0; j < 4; j++) {
        int col = cb + j * 16;
        if (col < NUM_CLASSES) {
            float bias = base_b[col];
            #pragma unroll
            for (int i = 0; i < 4; i++) {
                int r0 = rb + i * 16;
                out[(size_t)(r0 + 0) * NUM_CLASSES + col] = acc[i][j][0] + bias;
                out[(size_t)(r0 + 1) * NUM_CLASSES + col] = acc[i][j][1] + bias;
                out[(size_t)(r0 + 2) * NUM_CLASSES + col] = acc[i][j][2] + bias;
                out[(size_t)(r0 + 3) * NUM_CLASSES + col] = acc[i][j][3] + bias;
            }
        }
    }
}

extern "C" void kernel_launch(void* const* d_in, const int* in_sizes, int n_in,
                              void* d_out, int out_size, void* d_ws, size_t ws_size,
                              hipStream_t stream) {
    const float* x       = (const float*)d_in[0];
    const float* context = (const float*)d_in[1];
    const float* base_w  = (const float*)d_in[2];
    const float* base_b  = (const float*)d_in[3];
    const float* ctx_w   = (const float*)d_in[4];
    const float* ctx_b   = (const float*)d_in[5];
    const float* ln_g    = (const float*)d_in[6];
    const float* ln_b    = (const float*)d_in[7];
    const float* coeff_w = (const float*)d_in[8];
    const float* coeff_b = (const float*)d_in[9];
    const float* basis_A = (const float*)d_in[10];
    const float* basis_B = (const float*)d_in[11];
    float* out = (float*)d_out;

    uint8_t* ws = (uint8_t*)d_ws;
    const size_t szA    = (size_t)B_ROWS * KE * 2;      // 8,519,680
    const size_t szCoef = (size_t)B_ROWS * N_BASIS * 4; // 65,536
    const size_t szWT   = (size_t)D_MODEL * HIDDEN * 4; // 1,048,576
    const size_t szAT   = (size_t)D_MODEL * 32 * 4;     // 262,144
    const size_t szBext = (size_t)N_PAD * KE * 2;       // 209,264,640
    const size_t base   = szA + szCoef + szWT + szAT;
    const bool full = ws_size >= base + szBext;

    uint16_t* Aext    = (uint16_t*)ws;
    float*    coeffs  = (float*)(ws + szA);
    float*    ctx_wT  = (float*)(ws + szA + szCoef);
    float*    basisAT = (float*)(ws + szA + szCoef + szWT);
    uint16_t* Bbuf    = (uint16_t*)(ws + base);

    k_cvt_x<<<2048, 256, 0, stream>>>(x, Aext);
    k_transpose<<<(HIDDEN * D_MODEL + 255) / 256, 256, 0, stream>>>(ctx_w, ctx_wT, HIDDEN, D_MODEL);
    k_transpose<<<(32 * D_MODEL + 255) / 256, 256, 0, stream>>>(basis_A, basisAT, 32, D_MODEL);
    if (full) {
        k_cvt_bw<<<N_PAD, 256, 0, stream>>>(base_w, basis_B, Bbuf);
    } else {
        k_cvt_bbt<<<(N_PAD + 255) / 256, 256, 0, stream>>>(basis_B, Bbuf, 32, 0);
    }
    k_ctx<<<2048, HIDDEN, 0, stream>>>(context, ctx_wT, ctx_b, ln_g, ln_b,
                                       coeff_w, coeff_b, coeffs);
    k_zu<<<2048, 128, 0, stream>>>(x, basisAT, coeffs, Aext);

    if (full) k_gemm<true ><<<NTILES, 256, 0, stream>>>(Aext, Bbuf, base_w, base_b, out);
    else      k_gemm<false><<<NTILES, 256, 0, stream>>>(Aext, Bbuf, base_w, base_b, out);
}

// Round 2
// 1477.336 us; speedup vs baseline: 1.3305x; 1.0348x over previous
//
#include <hip/hip_runtime.h>
#include <cstdint>
#include <cstddef>

#define D_MODEL 2048
#define NUM_CLASSES 50257
#define N_PAD 50304          // fallback 128-tile padding (393*128)
#define N_PAD2 50432         // 197*256
#define N_BASIS 8
#define RANK 4
#define HIDDEN 128
#define B_ROWS 2048
#define KE 2080              // D_MODEL + N_BASIS*RANK
#define KP 2112              // KE padded to 33*64
#define KPB (KP*2)
#define NTK 33               // KP/64 K-tiles
#define NTILES 6288          // fallback grid (16*393)
#define NT2 1576             // 8 bm * 197 bn
#define LN_EPS 1e-5f

typedef short short8 __attribute__((ext_vector_type(8)));
typedef float f32x4 __attribute__((ext_vector_type(4)));

__device__ __forceinline__ uint16_t f2bf(float f) {
    union { float f; uint32_t u; } c; c.f = f;
    uint32_t r = c.u + 0x7FFFu + ((c.u >> 16) & 1u);   // round-to-nearest-even
    return (uint16_t)(r >> 16);
}

__device__ __forceinline__ short8 pack8(float4 a, float4 b) {
    union { short8 v; uint16_t u[8]; } p;
    p.u[0] = f2bf(a.x); p.u[1] = f2bf(a.y); p.u[2] = f2bf(a.z); p.u[3] = f2bf(a.w);
    p.u[4] = f2bf(b.x); p.u[5] = f2bf(b.y); p.u[6] = f2bf(b.z); p.u[7] = f2bf(b.w);
    return p.v;
}

__device__ __forceinline__ short8 zero8() {
    union { short8 s; uint16_t u[8]; } z;
    #pragma unroll
    for (int i = 0; i < 8; i++) z.u[i] = 0;
    return z.s;
}

__device__ __forceinline__ void async16(const void* g, void* l) {
    __builtin_amdgcn_global_load_lds(
        (const __attribute__((address_space(1))) unsigned int*)g,
        (__attribute__((address_space(3))) unsigned int*)l, 16, 0, 0);
}

// st_16x32-style XOR swizzle on byte offsets within a 16 KiB half-tile
__device__ __forceinline__ int swz(int q) { return q ^ (((q >> 9) & 1) << 5); }

#define BARRIER() do { asm volatile("" ::: "memory"); \
    __builtin_amdgcn_s_barrier(); asm volatile("" ::: "memory"); } while (0)

// ---- x (fp32, 2048x2048) -> Aext bf16 cols [0,2048), zeros [2048,2112), ld=KP ----
__global__ void k_cvt_x(const float* __restrict__ x, uint16_t* __restrict__ Aext) {
    int chunk = blockIdx.x * 256 + threadIdx.x;     // 2048*264 chunks of 8
    int b = chunk / 264, c8 = (chunk - b * 264) * 8;
    short8 v;
    if (c8 < D_MODEL) {
        const float4* src = (const float4*)(x + (size_t)b * D_MODEL + c8);
        v = pack8(src[0], src[1]);
    } else v = zero8();
    *(short8*)(Aext + (size_t)b * KP + c8) = v;
}

// ---- generic fp32 transpose: src[R][C] -> dst[C][R], write-coalesced ----
__global__ void k_transpose(const float* __restrict__ src, float* __restrict__ dst,
                            int R, int C) {
    int i = blockIdx.x * 256 + threadIdx.x;
    if (i >= R * C) return;
    int c = i / R, r = i - c * R;
    dst[i] = src[(size_t)r * C + c];
}

// ---- base_w + basis_B -> Bext bf16: cols [0,2048) base_w; [2048,2080) basis_B;
//      [2080,2112) zero; rows [NUM_CLASSES, N_PAD2) zero; ld=KP ----
__global__ void k_cvt_bw(const float* __restrict__ bw, const float* __restrict__ bB,
                         uint16_t* __restrict__ Bext) {
    int row = blockIdx.x;                 // 0..N_PAD2-1
    int c8 = threadIdx.x * 8;
    bool valid = row < NUM_CLASSES;
    short8 v;
    if (valid) {
        const float4* src = (const float4*)(bw + (size_t)row * D_MODEL + c8);
        v = pack8(src[0], src[1]);
    } else v = zero8();
    *(short8*)(Bext + (size_t)row * KP + c8) = v;
    if (threadIdx.x < 8) {
        int t = threadIdx.x;
        short8 e = zero8();
        if (valid && t < 4) {
            float4 v0 = *(const float4*)(bB + ((size_t)(2*t)   * NUM_CLASSES + row) * RANK);
            float4 v1 = *(const float4*)(bB + ((size_t)(2*t+1) * NUM_CLASSES + row) * RANK);
            e = pack8(v0, v1);
        }
        *(short8*)(Bext + (size_t)row * KP + D_MODEL + t * 8) = e;
    }
}

// ---- fallback: basis_B -> Bbt[row][32] bf16 ----
__global__ void k_cvt_bbt(const float* __restrict__ bB, uint16_t* __restrict__ dst,
                          int ld, int coloff) {
    int row = blockIdx.x * 256 + threadIdx.x;
    if (row >= N_PAD) return;
    union { short8 v[4]; uint16_t u[32]; } p;
    if (row < NUM_CLASSES) {
        #pragma unroll
        for (int nb = 0; nb < N_BASIS; nb++) {
            float4 v = *(const float4*)(bB + ((size_t)nb * NUM_CLASSES + row) * RANK);
            p.u[nb*4+0] = f2bf(v.x); p.u[nb*4+1] = f2bf(v.y);
            p.u[nb*4+2] = f2bf(v.z); p.u[nb*4+3] = f2bf(v.w);
        }
    } else {
        #pragma unroll
        for (int i = 0; i < 32; i++) p.u[i] = 0;
    }
    uint16_t* d = dst + (size_t)row * ld + coloff;
    #pragma unroll
    for (int i = 0; i < 4; i++) *(short8*)(d + i * 8) = p.v[i];
}

// ---- context MLP (ctx_wT is [D_MODEL][HIDDEN], coalesced) ----
__global__ void k_ctx(const float* __restrict__ context, const float* __restrict__ ctx_wT,
                      const float* __restrict__ ctx_b, const float* __restrict__ ln_g,
                      const float* __restrict__ ln_b, const float* __restrict__ coeff_w,
                      const float* __restrict__ coeff_b, float* __restrict__ coeffs) {
    __shared__ float sctx[D_MODEL];
    __shared__ float s1[HIDDEN], s2[HIDDEN], sh[HIDDEN];
    int tid = threadIdx.x, b = blockIdx.x;
    const float4* csrc = (const float4*)(context + (size_t)b * D_MODEL);
    for (int i = tid; i < D_MODEL / 4; i += HIDDEN) ((float4*)sctx)[i] = csrc[i];
    __syncthreads();
    float a0 = 0.f, a1 = 0.f, a2 = 0.f, a3 = 0.f;
    #pragma unroll 4
    for (int k = 0; k < D_MODEL; k += 4) {
        a0 += ctx_wT[(size_t)(k + 0) * HIDDEN + tid] * sctx[k + 0];
        a1 += ctx_wT[(size_t)(k + 1) * HIDDEN + tid] * sctx[k + 1];
        a2 += ctx_wT[(size_t)(k + 2) * HIDDEN + tid] * sctx[k + 2];
        a3 += ctx_wT[(size_t)(k + 3) * HIDDEN + tid] * sctx[k + 3];
    }
    float h0 = (a0 + a1) + (a2 + a3) + ctx_b[tid];
    s1[tid] = h0; s2[tid] = h0 * h0;
    __syncthreads();
    for (int off = HIDDEN / 2; off > 0; off >>= 1) {
        if (tid < off) { s1[tid] += s1[tid + off]; s2[tid] += s2[tid + off]; }
        __syncthreads();
    }
    float mu  = s1[0] * (1.f / HIDDEN);
    float var = s2[0] * (1.f / HIDDEN) - mu * mu;
    float hn = (h0 - mu) * rsqrtf(var + LN_EPS) * ln_g[tid] + ln_b[tid];
    float h = 0.5f * hn * (1.f + erff(hn * 0.70710678118654752f));
    sh[tid] = h;
    __syncthreads();
    if (tid < N_BASIS) {
        const float* cw = coeff_w + tid * HIDDEN;
        float a = 0.f;
        #pragma unroll 4
        for (int k = 0; k < HIDDEN; k++) a += cw[k] * sh[k];
        coeffs[b * N_BASIS + tid] = a + coeff_b[tid];
    }
}

// ---- z/u: t = x @ basis_A^T ; z = coeffs.t ; u -> Aext cols [2048,2080) ----
__global__ void k_zu(const float* __restrict__ x, const float* __restrict__ basis_AT,
                     const float* __restrict__ coeffs, uint16_t* __restrict__ Aext) {
    __shared__ float sx[D_MODEL];
    __shared__ float part[128];
    __shared__ float st[32];
    __shared__ float sz[RANK];
    int tid = threadIdx.x, b = blockIdx.x;
    const float4* xs = (const float4*)(x + (size_t)b * D_MODEL);
    for (int i = tid; i < D_MODEL / 4; i += 128) ((float4*)sx)[i] = xs[i];
    __syncthreads();
    int j = tid & 31, s = tid >> 5;
    int k0 = s * (D_MODEL / 4);
    float a0 = 0.f, a1 = 0.f, a2 = 0.f, a3 = 0.f;
    #pragma unroll 4
    for (int k = 0; k < D_MODEL / 4; k += 4) {
        a0 += basis_AT[(size_t)(k0 + k + 0) * 32 + j] * sx[k0 + k + 0];
        a1 += basis_AT[(size_t)(k0 + k + 1) * 32 + j] * sx[k0 + k + 1];
        a2 += basis_AT[(size_t)(k0 + k + 2) * 32 + j] * sx[k0 + k + 2];
        a3 += basis_AT[(size_t)(k0 + k + 3) * 32 + j] * sx[k0 + k + 3];
    }
    part[tid] = (a0 + a1) + (a2 + a3);
    __syncthreads();
    if (tid < 32) st[tid] = part[tid] + part[tid + 32] + part[tid + 64] + part[tid + 96];
    __syncthreads();
    if (tid < RANK) {
        float z = 0.f;
        #pragma unroll
        for (int nb = 0; nb < N_BASIS; nb++) z += coeffs[b * N_BASIS + nb] * st[nb * RANK + tid];
        sz[tid] = z;
    }
    __syncthreads();
    if (tid < 32) {
        int nb = tid >> 2, r = tid & 3;
        float u = coeffs[b * N_BASIS + nb] * sz[r];
        Aext[(size_t)b * KP + D_MODEL + tid] = f2bf(u);
    }
}

// ================= 256x256 8-phase GEMM (T2+T3+T4+T5) =================
// C[m,n] = sum_k Aext[m,k]*Bext[n,k] + base_b[n]
// 512 thr = 8 waves (2Mx4N); BK=64 as two K-halves of 32; LDS 128 KiB
// (2 slots x 2 khalves x [256 rows][32 cols] bf16 for each of A,B).
// Stage->first-read distance 6-7 phases; vmcnt(6) once per K-tile.
#define MMA_BLOCK(IG) do {                                                      \
    __builtin_amdgcn_s_setprio(1);                                              \
    _Pragma("unroll")                                                           \
    for (int t = 0; t < 4; t++) {                                               \
        _Pragma("unroll")                                                       \
        for (int jj = 0; jj < 4; jj++)                                          \
            acc[(IG)*4 + t][jj] = __builtin_amdgcn_mfma_f32_16x16x32_bf16(      \
                af[t], bf[jj], acc[(IG)*4 + t][jj], 0, 0, 0);                   \
    }                                                                           \
    __builtin_amdgcn_s_setprio(0);                                              \
} while (0)

__global__ __launch_bounds__(512, 2) void k_gemm256(
        const uint16_t* __restrict__ Aext,   // 2048 x KP bf16
        const uint16_t* __restrict__ Bext,   // N_PAD2 x KP bf16
        const float* __restrict__ base_b,
        float* __restrict__ out) {
    __shared__ __align__(16) uint16_t sA[2][2][8192];   // [slot][khalf][256*32]
    __shared__ __align__(16) uint16_t sB[2][2][8192];
    const int tid = threadIdx.x;
    const int lane = tid & 63, w = tid >> 6;
    const int wm = w >> 2, wn = w & 3;
    // bm = blockIdx%8: each XCD owns one bm -> its 1.08 MB A-panel stays L2-resident
    const int bm = blockIdx.x & 7, bn = blockIdx.x >> 3;

    // swizzled ds_read byte offsets within a 16 KiB half (loop-invariant)
    int aoff[2][4], boff[4];
    #pragma unroll
    for (int ig = 0; ig < 2; ig++)
        #pragma unroll
        for (int t = 0; t < 4; t++) {
            int r = wm * 128 + (ig * 4 + t) * 16 + (lane & 15);
            aoff[ig][t] = swz(r * 64 + (lane >> 4) * 16);
        }
    #pragma unroll
    for (int j = 0; j < 4; j++) {
        int n = wn * 64 + j * 16 + (lane & 15);
        boff[j] = swz(n * 64 + (lane >> 4) * 16);
    }

    // stage geometry: lds physical p is linear; global src pre-swizzled (rule 21)
    const uint8_t* Aeb = (const uint8_t*)Aext;
    const uint8_t* Beb = (const uint8_t*)Bext;
    const int p0 = w * 1024 + lane * 16, p1 = p0 + 8192;
    const int q0 = swz(p0), q1 = swz(p1);
    const uint8_t* gA0 = Aeb + (size_t)(bm * 256 + (q0 >> 6)) * KPB + (q0 & 63);
    const uint8_t* gA1 = Aeb + (size_t)(bm * 256 + (q1 >> 6)) * KPB + (q1 & 63);
    const uint8_t* gB0 = Beb + (size_t)(bn * 256 + (q0 >> 6)) * KPB + (q0 & 63);
    const uint8_t* gB1 = Beb + (size_t)(bn * 256 + (q1 >> 6)) * KPB + (q1 & 63);
    uint8_t* sAb = (uint8_t*)sA;
    uint8_t* sBb = (uint8_t*)sB;
    const int ldst = w * 1024;             // wave-uniform LDS dest (+lane*16 by HW)

    auto stA = [&](int T, int kh) {
        uint8_t* d = sAb + (T & 1) * 32768 + kh * 16384;
        int co = T * 128 + kh * 64;        // column byte offset
        async16(gA0 + co, d + ldst);
        async16(gA1 + co, d + 8192 + ldst);
    };
    auto stB = [&](int T, int kh) {
        uint8_t* d = sBb + (T & 1) * 32768 + kh * 16384;
        int co = T * 128 + kh * 64;
        async16(gB0 + co, d + ldst);
        async16(gB1 + co, d + 8192 + ldst);
    };

    f32x4 acc[8][4] = {};
    short8 af[4], bf[4];

    // prologue: tile0 all 4 halves + tile1 first 3 (issue order = steady state)
    stB(0, 0); stA(0, 0); stB(0, 1); stA(0, 1);
    stB(1, 0); stA(1, 0); stB(1, 1);
    asm volatile("s_waitcnt vmcnt(6)" ::: "memory");   // tile0 fully landed
    BARRIER();

    #pragma unroll 1
    for (int a = 0; a < NTK; ++a) {
        const int slot = a & 1;
        const uint8_t* hA0 = sAb + slot * 32768;
        const uint8_t* hA1 = hA0 + 16384;
        const uint8_t* hB0 = sBb + slot * 32768;
        const uint8_t* hB1 = hB0 + 16384;

        // phase 0: read A-kh0(ig0) + B-kh0; stage A-kh1(a+1)
        #pragma unroll
        for (int t = 0; t < 4; t++) af[t] = *(const short8*)(hA0 + aoff[0][t]);
        #pragma unroll
        for (int j = 0; j < 4; j++) bf[j] = *(const short8*)(hB0 + boff[j]);
        if (a + 1 < NTK) stA(a + 1, 1);
        BARRIER();
        asm volatile("s_waitcnt lgkmcnt(0)" ::: "memory");
        MMA_BLOCK(0);
        BARRIER();

        // phase 1: read A-kh0(ig1); stage B-kh0(a+2)
        #pragma unroll
        for (int t = 0; t < 4; t++) af[t] = *(const short8*)(hA0 + aoff[1][t]);
        if (a + 2 < NTK) stB(a + 2, 0);
        BARRIER();
        asm volatile("s_waitcnt lgkmcnt(0)" ::: "memory");
        MMA_BLOCK(1);
        BARRIER();

        // phase 2: read A-kh1(ig0) + B-kh1; stage A-kh0(a+2)
        #pragma unroll
        for (int t = 0; t < 4; t++) af[t] = *(const short8*)(hA1 + aoff[0][t]);
        #pragma unroll
        for (int j = 0; j < 4; j++) bf[j] = *(const short8*)(hB1 + boff[j]);
        if (a + 2 < NTK) stA(a + 2, 0);
        BARRIER();
        asm volatile("s_waitcnt lgkmcnt(0)" ::: "memory");
        MMA_BLOCK(0);
        BARRIER();

        // phase 3: read A-kh1(ig1); stage B-kh1(a+2); counted vmcnt (never 0 mid-loop)
        #pragma unroll
        for (int t = 0; t < 4; t++) af[t] = *(const short8*)(hA1 + aoff[1][t]);
        if (a + 2 < NTK) stB(a + 2, 1);
        if (a < NTK - 2) asm volatile("s_waitcnt vmcnt(6)" ::: "memory");
        else             asm volatile("s_waitcnt vmcnt(0)" ::: "memory");
        BARRIER();
        asm volatile("s_waitcnt lgkmcnt(0)" ::: "memory");
        MMA_BLOCK(1);
        BARRIER();
    }

    // epilogue
    const int rb = bm * 256 + wm * 128 + ((lane >> 4) << 2);
    const int cb = bn * 256 + wn * 64 + (lane & 15);
    #pragma unroll
    for (int j = 0; j < 4; j++) {
        int col = cb + j * 16;
        if (col < NUM_CLASSES) {
            float bias = base_b[col];
            #pragma unroll
            for (int i = 0; i < 8; i++) {
                int r0 = rb + i * 16;
                out[(size_t)(r0 + 0) * NUM_CLASSES + col] = acc[i][j][0] + bias;
                out[(size_t)(r0 + 1) * NUM_CLASSES + col] = acc[i][j][1] + bias;
                out[(size_t)(r0 + 2) * NUM_CLASSES + col] = acc[i][j][2] + bias;
                out[(size_t)(r0 + 3) * NUM_CLASSES + col] = acc[i][j][3] + bias;
            }
        }
    }
}

// ---- fallback 128x128 GEMM (workspace too small for Bext): stage B from fp32 ----
__global__ __launch_bounds__(256) void k_gemm128(
        const uint16_t* __restrict__ Aext,   // B_ROWS x KP bf16
        const uint16_t* __restrict__ Bbt,    // N_PAD x 32 bf16
        const float* __restrict__ bw,
        const float* __restrict__ base_b,
        float* __restrict__ out) {
    __shared__ uint16_t sA[2][128 * 32];
    __shared__ uint16_t sB[2][128 * 32];
    const int tid = threadIdx.x;
    const int lane = tid & 63, w = tid >> 6;
    const int l = blockIdx.x;
    const int tile = (l & 7) * (NTILES / 8) + (l >> 3);
    const int bm = tile & 15, bn = tile >> 4;
    const int wm = (w >> 1) * 64, wn = (w & 1) * 64;
    const int sr = tid >> 2, sc = (tid & 3) * 8;
    f32x4 acc[4][4] = {};

    const uint16_t* gA = Aext + (size_t)(bm * 128 + sr) * KP + sc;

    auto stageA = [&](int kk, int sel) {
        async16(gA + kk, &sA[sel][w * 512]);
        async16(gA + (size_t)64 * KP + kk, &sA[sel][2048 + w * 512]);
    };
    auto stageB = [&](int kk, int sel) {
        if (kk < D_MODEL) {
            #pragma unroll
            for (int it = 0; it < 2; it++) {
                int rr = it * 64 + sr;
                int gr = bn * 128 + rr;
                short8 v;
                if (gr < NUM_CLASSES) {
                    const float4* src = (const float4*)(bw + (size_t)gr * D_MODEL + kk + sc);
                    v = pack8(src[0], src[1]);
                } else v = zero8();
                *(short8*)(&sB[sel][rr * 32 + sc]) = v;
            }
        } else {
            #pragma unroll
            for (int it = 0; it < 2; it++) {
                int rr = it * 64 + sr;
                async16(Bbt + (size_t)(bn * 128 + rr) * 32 + (kk - D_MODEL) + sc,
                        &sB[sel][it * 2048 + w * 512]);
            }
        }
    };

    stageA(0, 0); stageB(0, 0);
    __syncthreads();
    int cur = 0;
    for (int kk = 0; kk < KE; kk += 32) {
        int nxt = cur ^ 1;
        if (kk + 32 < KE) { stageA(kk + 32, nxt); stageB(kk + 32, nxt); }
        short8 af[4], bfv[4];
        #pragma unroll
        for (int i = 0; i < 4; i++)
            af[i] = *(const short8*)(&sA[cur][(wm + i * 16 + (lane & 15)) * 32] + (lane >> 4) * 8);
        #pragma unroll
        for (int j = 0; j < 4; j++)
            bfv[j] = *(const short8*)(&sB[cur][(wn + j * 16 + (lane & 15)) * 32] + (lane >> 4) * 8);
        #pragma unroll
        for (int i = 0; i < 4; i++)
            #pragma unroll
            for (int j = 0; j < 4; j++)
                acc[i][j] = __builtin_amdgcn_mfma_f32_16x16x32_bf16(af[i], bfv[j], acc[i][j], 0, 0, 0);
        __syncthreads();
        cur = nxt;
    }

    const int rb = bm * 128 + wm + ((lane >> 4) << 2);
    const int cb = bn * 128 + wn + (lane & 15);
    #pragma unroll
    for (int j = 0; j < 4; j++) {
        int col = cb + j * 16;
        if (col < NUM_CLASSES) {
            float bias = base_b[col];
            #pragma unroll
            for (int i = 0; i < 4; i++) {
                int r0 = rb + i * 16;
                out[(size_t)(r0 + 0) * NUM_CLASSES + col] = acc[i][j][0] + bias;
                out[(size_t)(r0 + 1) * NUM_CLASSES + col] = acc[i][j][1] + bias;
                out[(size_t)(r0 + 2) * NUM_CLASSES + col] = acc[i][j][2] + bias;
                out[(size_t)(r0 + 3) * NUM_CLASSES + col] = acc[i][j][3] + bias;
            }
        }
    }
}

extern "C" void kernel_launch(void* const* d_in, const int* in_sizes, int n_in,
                              void* d_out, int out_size, void* d_ws, size_t ws_size,
                              hipStream_t stream) {
    const float* x       = (const float*)d_in[0];
    const float* context = (const float*)d_in[1];
    const float* base_w  = (const float*)d_in[2];
    const float* base_b  = (const float*)d_in[3];
    const float* ctx_w   = (const float*)d_in[4];
    const float* ctx_b   = (const float*)d_in[5];
    const float* ln_g    = (const float*)d_in[6];
    const float* ln_b    = (const float*)d_in[7];
    const float* coeff_w = (const float*)d_in[8];
    const float* coeff_b = (const float*)d_in[9];
    const float* basis_A = (const float*)d_in[10];
    const float* basis_B = (const float*)d_in[11];
    float* out = (float*)d_out;

    uint8_t* ws = (uint8_t*)d_ws;
    const size_t szA    = (size_t)B_ROWS * KP * 2;      // 8,650,752
    const size_t szCoef = (size_t)B_ROWS * N_BASIS * 4; // 65,536
    const size_t szWT   = (size_t)D_MODEL * HIDDEN * 4; // 1,048,576
    const size_t szAT   = (size_t)D_MODEL * 32 * 4;     // 262,144
    const size_t szBext = (size_t)N_PAD2 * KP * 2;      // 213,024,768
    const size_t szBbt  = (size_t)N_PAD * 32 * 2;
    const size_t base   = szA + szCoef + szWT + szAT;
    const bool full = ws_size >= base + szBext;

    uint16_t* Aext    = (uint16_t*)ws;
    float*    coeffs  = (float*)(ws + szA);
    float*    ctx_wT  = (float*)(ws + szA + szCoef);
    float*    basisAT = (float*)(ws + szA + szCoef + szWT);
    uint16_t* Bbuf    = (uint16_t*)(ws + base);

    k_cvt_x<<<2112, 256, 0, stream>>>(x, Aext);
    k_transpose<<<(HIDDEN * D_MODEL + 255) / 256, 256, 0, stream>>>(ctx_w, ctx_wT, HIDDEN, D_MODEL);
    k_transpose<<<(32 * D_MODEL + 255) / 256, 256, 0, stream>>>(basis_A, basisAT, 32, D_MODEL);
    if (full) {
        k_cvt_bw<<<N_PAD2, 256, 0, stream>>>(base_w, basis_B, Bbuf);
    } else {
        k_cvt_bbt<<<(N_PAD + 255) / 256, 256, 0, stream>>>(basis_B, Bbuf, 32, 0);
    }
    k_ctx<<<2048, HIDDEN, 0, stream>>>(context, ctx_wT, ctx_b, ln_g, ln_b,
                                       coeff_w, coeff_b, coeffs);
    k_zu<<<2048, 128, 0, stream>>>(x, basisAT, coeffs, Aext);

    if (full) k_gemm256<<<NT2, 512, 0, stream>>>(Aext, Bbuf, base_b, out);
    else      k_gemm128<<<NTILES, 256, 0, stream>>>(Aext, Bbuf, base_w, base_b, out);
}